// Round 1
// baseline (793.523 us; speedup 1.0000x reference)
//
#include <hip/hip_runtime.h>
#include <math.h>

// Problem constants (from reference setup_inputs)
#define B_  32
#define T_  2048
#define C_  2048
#define E_  64
#define NT_ 8            // T-chunks for the partial reduction
#define TC_ (T_ / NT_)   // 256 timesteps per chunk
#define C4_ (C_ / 4)     // 512 float4 per channel row

// d_out layout (floats), outputs concatenated in reference return order:
// [0] active_expert_probs [B,T,E]; [1] fallback_count (1); [2] logits [B,E]; [3] activation_mask [B,T,E]
#define OFF_FB     (B_ * T_ * E_)          // 4194304
#define OFF_LOGITS (OFF_FB + 1)            // 4194305
#define OFF_MASK   (OFF_LOGITS + B_ * E_)  // 4196353 (NOT 16B-aligned -> scalar stores there)

// d_ws layout (floats)
#define WS_PARTIAL 0                        // NT_*B_*C_ = 524288 floats (2 MB)
#define WS_FLAGS   (NT_ * B_ * C_)          // B_ floats
#define WS_PROBS   (WS_FLAGS + B_)          // B_*E_ floats
#define WS_MASK    (WS_PROBS + B_ * E_)     // B_*E_ floats

// ---------------------------------------------------------------------------
// K1: partial sums of hidden_states over T-chunks.
// One thread per (b, t-chunk, float4-column). 131072 threads = 2048 waves
// = 8 waves/CU; 16B/lane coalesced loads -> HBM-bound.
// ---------------------------------------------------------------------------
__global__ __launch_bounds__(256) void k_partial(const float* __restrict__ hs,
                                                 float* __restrict__ partial) {
    int gid = blockIdx.x * 256 + threadIdx.x;      // 0 .. B_*NT_*C4_-1
    int c4  = gid & (C4_ - 1);
    int r   = gid >> 9;                            // / C4_
    int tc  = r & (NT_ - 1);
    int b   = r >> 3;                              // / NT_

    const float4* hs4 = (const float4*)hs;
    long base = (long)(b * T_ + tc * TC_) * C4_ + c4;

    float4 a0 = make_float4(0.f, 0.f, 0.f, 0.f);
    float4 a1 = make_float4(0.f, 0.f, 0.f, 0.f);
    #pragma unroll 4
    for (int t = 0; t < TC_; t += 2) {
        float4 v0 = hs4[base + (long)t * C4_];
        float4 v1 = hs4[base + (long)(t + 1) * C4_];
        a0.x += v0.x; a0.y += v0.y; a0.z += v0.z; a0.w += v0.w;
        a1.x += v1.x; a1.y += v1.y; a1.z += v1.z; a1.w += v1.w;
    }
    float4 acc = make_float4(a0.x + a1.x, a0.y + a1.y, a0.z + a1.z, a0.w + a1.w);

    float4* p4 = (float4*)partial;
    p4[(tc * B_ + b) * C4_ + c4] = acc;            // coalesced 16B store
}

// ---------------------------------------------------------------------------
// K2: full gating for one batch row per block (32 blocks x 256 threads).
// 4 waves split the C dimension; lane = expert. Folds the partial-reduce,
// 1/T mean, both L2 norms, and the affinity dot into one pass.
// Wave 0 then does mask / exact-top_k-fallback / masked softmax.
// ---------------------------------------------------------------------------
__global__ __launch_bounds__(256) void k_gate(const float* __restrict__ partial,
                                              const float* __restrict__ sim,
                                              const float* __restrict__ gates,
                                              float* __restrict__ out,
                                              float* __restrict__ ws_probs,
                                              float* __restrict__ ws_mask,
                                              float* __restrict__ ws_flags) {
    int b    = blockIdx.x;
    int tid  = threadIdx.x;
    int e    = tid & 63;    // expert = lane
    int wseg = tid >> 6;    // which wave -> which C-range

    __shared__ float red0[4][64];
    __shared__ float red1[4][64];
    __shared__ float red2[4][64];
    __shared__ float lds_logit[64];

    float dot = 0.f, wsq = 0.f, ssq = 0.f;
    const float invT = 1.0f / (float)T_;
    int c0 = wseg * (C_ / 4);
    for (int c = c0; c < c0 + C_ / 4; ++c) {
        float s = 0.f;
        #pragma unroll
        for (int tc = 0; tc < NT_; ++tc)
            s += partial[(tc * B_ + b) * C_ + c];  // broadcast (same addr across lanes)
        s *= invT;                                  // seq_rep mean
        float w = sim[c * E_ + e];                  // coalesced over lanes
        dot = fmaf(s, w, dot);
        wsq = fmaf(w, w, wsq);
        ssq = fmaf(s, s, ssq);
    }
    red0[wseg][e] = dot;
    red1[wseg][e] = wsq;
    red2[wseg][e] = ssq;
    __syncthreads();

    float logit = 0.f;
    bool  active = false;
    if (tid < 64) {
        dot = red0[0][e] + red0[1][e] + red0[2][e] + red0[3][e];
        wsq = red1[0][e] + red1[1][e] + red1[2][e] + red1[3][e];
        ssq = red2[0][e] + red2[1][e] + red2[2][e] + red2[3][e];
        float ns  = fmaxf(sqrtf(ssq), 1e-12f);      // F.normalize eps
        float nw  = fmaxf(sqrtf(wsq), 1e-12f);
        float aff = dot / (ns * nw);
        float g   = gates[e];
        float sig = 1.0f / (1.0f + expf(-g));
        logit  = aff - sig;
        active = (logit > 0.0f);
        lds_logit[e] = logit;
    }
    __syncthreads();   // non-divergent barrier before cross-lane reads

    if (tid < 64) {
        unsigned long long bal = __ballot(active);  // wave 0 only; 64-bit mask
        bool inactive = (bal == 0ULL);

        // exact lax.top_k tie-breaking: rank = #{j : lj>li or (lj==li and j<i)}
        int rank = 0;
        for (int j = 0; j < 64; ++j) {
            float lj = lds_logit[j];
            rank += (int)((lj > logit) || (lj == logit && j < e));
        }
        bool fb = (rank < (E_ / 2));
        bool m  = inactive ? fb : active;           // max(active, fb) with active==0

        float gated = fmaxf(logit, 0.0f);
        float me = m ? gated : -3.402823466e38f;    // -finfo(f32).max, like reference

        float mx = me;
        #pragma unroll
        for (int off = 1; off < 64; off <<= 1)
            mx = fmaxf(mx, __shfl_xor(mx, off, 64));
        float p = expf(me - mx);                    // underflows to 0 for masked-out
        float sum = p;
        #pragma unroll
        for (int off = 1; off < 64; off <<= 1)
            sum += __shfl_xor(sum, off, 64);
        float prob = p / sum;

        out[OFF_LOGITS + b * E_ + e] = logit;
        ws_probs[b * E_ + e] = prob;
        ws_mask[b * E_ + e]  = m ? 1.0f : 0.0f;
        if (e == 0) ws_flags[b] = inactive ? 1.0f : 0.0f;
    }
}

// ---------------------------------------------------------------------------
// K3: broadcast probs/mask over T and write fallback_count.
// Scalar stores (mask region base is not 16B-aligned) — still fully
// coalesced: consecutive lanes -> consecutive dwords.
// ---------------------------------------------------------------------------
__global__ __launch_bounds__(256) void k_bcast(const float* __restrict__ ws_probs,
                                               const float* __restrict__ ws_mask,
                                               const float* __restrict__ ws_flags,
                                               float* __restrict__ out) {
    int gid = blockIdx.x * 256 + threadIdx.x;       // 0 .. B_*T_*E_-1
    int e   = gid & (E_ - 1);
    int bt  = gid >> 6;
    int b   = bt >> 11;                             // / T_
    float p = ws_probs[b * E_ + e];                 // L1-resident after first touch
    float m = ws_mask[b * E_ + e];
    out[gid] = p;
    out[OFF_MASK + gid] = m;
    if (gid == 0) {                                 // d_out is poisoned, must write
        float fc = 0.f;
        for (int i = 0; i < B_; ++i) fc += ws_flags[i];
        out[OFF_FB] = fc;
    }
}

extern "C" void kernel_launch(void* const* d_in, const int* in_sizes, int n_in,
                              void* d_out, int out_size, void* d_ws, size_t ws_size,
                              hipStream_t stream) {
    const float* hs    = (const float*)d_in[0];
    const float* sim   = (const float*)d_in[1];
    const float* gates = (const float*)d_in[2];
    float* out = (float*)d_out;
    float* ws  = (float*)d_ws;   // need (WS_MASK + B_*E_)*4 ≈ 2.11 MB of scratch

    float* partial = ws + WS_PARTIAL;
    float* flags   = ws + WS_FLAGS;
    float* probs   = ws + WS_PROBS;
    float* maskv   = ws + WS_MASK;

    hipLaunchKernelGGL(k_partial, dim3(B_ * NT_ * C4_ / 256), dim3(256), 0, stream,
                       hs, partial);
    hipLaunchKernelGGL(k_gate, dim3(B_), dim3(256), 0, stream,
                       partial, sim, gates, out, probs, maskv, flags);
    hipLaunchKernelGGL(k_bcast, dim3(B_ * T_ * E_ / 256), dim3(256), 0, stream,
                       probs, maskv, flags, out);
}

// Round 2
// 739.559 us; speedup vs baseline: 1.0730x; 1.0730x over previous
//
#include <hip/hip_runtime.h>
#include <math.h>

// Problem constants (from reference setup_inputs)
#define B_  32
#define T_  2048
#define C_  2048
#define E_  64
#define NT_ 16           // T-chunks for the partial reduction
#define TC_ (T_ / NT_)   // 128 timesteps per chunk
#define C4_ (C_ / 4)     // 512 float4 per channel row

// d_out layout (floats), outputs concatenated in reference return order:
// [0] active_expert_probs [B,T,E]; [1] fallback_count (1); [2] logits [B,E]; [3] activation_mask [B,T,E]
#define OFF_FB     (B_ * T_ * E_)          // 4194304
#define OFF_LOGITS (OFF_FB + 1)            // 4194305
#define OFF_MASK   (OFF_LOGITS + B_ * E_)  // 4196353 (OFF_MASK+3 is 16B-aligned)
#define NBT_       (B_ * T_ * E_)          // 4194304 elements per broadcast output
#define NQ_        (NBT_ / 4)              // 1048576 float4s

// d_ws layout (floats)
#define WS_PARTIAL 0                        // NT_*B_*C_ = 1048576 floats (4 MB)
#define WS_FLAGS   (NT_ * B_ * C_)          // B_ floats
#define WS_PROBS   (WS_FLAGS + B_)          // B_*E_ floats
#define WS_MASK    (WS_PROBS + B_ * E_)     // B_*E_ floats

// ---------------------------------------------------------------------------
// K1: partial sums of hidden_states over T-chunks. 537 MB read -> HBM-bound.
// 1024 blocks (4/CU, 16 waves/CU); 16B/lane coalesced loads, 4 in flight.
// ---------------------------------------------------------------------------
__global__ __launch_bounds__(256) void k_partial(const float* __restrict__ hs,
                                                 float* __restrict__ partial) {
    int gid = blockIdx.x * 256 + threadIdx.x;      // 0 .. B_*NT_*C4_-1
    int c4  = gid & (C4_ - 1);
    int r   = gid >> 9;                            // / C4_
    int tc  = r & (NT_ - 1);
    int b   = r >> 4;                              // / NT_

    const float4* hs4 = (const float4*)hs;
    int base = (b * T_ + tc * TC_) * C4_ + c4;     // max ~33.6M < 2^31

    float4 a0 = make_float4(0.f, 0.f, 0.f, 0.f);
    float4 a1 = a0, a2 = a0, a3 = a0;
    for (int t = 0; t < TC_; t += 4) {
        float4 v0 = hs4[base + (t + 0) * C4_];
        float4 v1 = hs4[base + (t + 1) * C4_];
        float4 v2 = hs4[base + (t + 2) * C4_];
        float4 v3 = hs4[base + (t + 3) * C4_];
        a0.x += v0.x; a0.y += v0.y; a0.z += v0.z; a0.w += v0.w;
        a1.x += v1.x; a1.y += v1.y; a1.z += v1.z; a1.w += v1.w;
        a2.x += v2.x; a2.y += v2.y; a2.z += v2.z; a2.w += v2.w;
        a3.x += v3.x; a3.y += v3.y; a3.z += v3.z; a3.w += v3.w;
    }
    float4 acc = make_float4(a0.x + a1.x + a2.x + a3.x,
                             a0.y + a1.y + a2.y + a3.y,
                             a0.z + a1.z + a2.z + a3.z,
                             a0.w + a1.w + a2.w + a3.w);
    ((float4*)partial)[(tc * B_ + b) * C4_ + c4] = acc;   // coalesced 16B store
}

// ---------------------------------------------------------------------------
// K2: gating for one batch row per block (32 blocks x 256 threads).
// Stage 1: seq_rep -> LDS via float4 lane-coalesced partial reads (no
//          wave-uniform scalar-load latency chains), ssq block-reduced once.
// Stage 2: dot loop reads sim coalesced (256B/wave-instr), s via LDS
//          broadcast (same-addr -> conflict-free).
// Epilogue (wave 0): mask / exact top_k fallback / masked softmax.
// ---------------------------------------------------------------------------
__global__ __launch_bounds__(256) void k_gate(const float* __restrict__ partial,
                                              const float* __restrict__ sim,
                                              const float* __restrict__ gates,
                                              float* __restrict__ out,
                                              float* __restrict__ ws_probs,
                                              float* __restrict__ ws_mask,
                                              float* __restrict__ ws_flags) {
    int b   = blockIdx.x;
    int tid = threadIdx.x;
    int e   = tid & 63;
    int w   = tid >> 6;

    __shared__ float s_sh[C_];          // seq_rep mean, 8 KB
    __shared__ float redd[4][64];
    __shared__ float redw[4][64];
    __shared__ float red_ssq[4];
    __shared__ float lds_logit[64];

    // ---- stage 1: seq_rep into LDS + ssq ----
    const float4* p4 = (const float4*)partial;
    float4 m0 = make_float4(0.f, 0.f, 0.f, 0.f);
    float4 m1 = m0;
    #pragma unroll
    for (int tc = 0; tc < NT_; ++tc) {
        int o = (tc * B_ + b) * C4_;
        float4 v0 = p4[o + tid];        // 256 lanes x 16B contiguous
        float4 v1 = p4[o + tid + 256];
        m0.x += v0.x; m0.y += v0.y; m0.z += v0.z; m0.w += v0.w;
        m1.x += v1.x; m1.y += v1.y; m1.z += v1.z; m1.w += v1.w;
    }
    const float invT = 1.0f / (float)T_;
    m0.x *= invT; m0.y *= invT; m0.z *= invT; m0.w *= invT;
    m1.x *= invT; m1.y *= invT; m1.z *= invT; m1.w *= invT;
    ((float4*)s_sh)[tid]       = m0;
    ((float4*)s_sh)[tid + 256] = m1;

    float ssq = m0.x * m0.x + m0.y * m0.y + m0.z * m0.z + m0.w * m0.w
              + m1.x * m1.x + m1.y * m1.y + m1.z * m1.z + m1.w * m1.w;
    #pragma unroll
    for (int off = 1; off < 64; off <<= 1)
        ssq += __shfl_xor(ssq, off, 64);
    if (e == 0) red_ssq[w] = ssq;
    __syncthreads();
    float ssq_tot = red_ssq[0] + red_ssq[1] + red_ssq[2] + red_ssq[3];

    // ---- stage 2: dot(seq_rep, sim[:,e]) + colnorm(sim), C split 4 ways ----
    float dot = 0.f, wsq = 0.f;
    int c0 = w * (C_ / 4);
    #pragma unroll 4
    for (int c = c0; c < c0 + C_ / 4; ++c) {
        float wv = sim[c * E_ + e];     // coalesced over lanes
        float sv = s_sh[c];             // LDS broadcast, conflict-free
        dot = fmaf(sv, wv, dot);
        wsq = fmaf(wv, wv, wsq);
    }
    redd[w][e] = dot;
    redw[w][e] = wsq;
    __syncthreads();

    // ---- epilogue on wave 0 ----
    float logit = 0.f;
    bool  active = false;
    if (tid < 64) {
        float d = redd[0][e] + redd[1][e] + redd[2][e] + redd[3][e];
        float q = redw[0][e] + redw[1][e] + redw[2][e] + redw[3][e];
        float ns  = fmaxf(sqrtf(ssq_tot), 1e-12f);   // F.normalize eps
        float nw  = fmaxf(sqrtf(q), 1e-12f);
        float aff = d / (ns * nw);
        float g   = gates[e];
        float sig = 1.0f / (1.0f + expf(-g));
        logit  = aff - sig;
        active = (logit > 0.0f);
        lds_logit[e] = logit;
    }
    __syncthreads();   // non-divergent barrier before cross-lane reads

    if (tid < 64) {
        unsigned long long bal = __ballot(active);   // 64-bit mask, wave=64
        bool inactive = (bal == 0ULL);

        // exact lax.top_k tie-breaking: rank = #{j : lj>li or (lj==li and j<i)}
        int rank = 0;
        #pragma unroll
        for (int j = 0; j < 64; ++j) {
            float lj = lds_logit[j];
            rank += (int)((lj > logit) || (lj == logit && j < e));
        }
        bool fb = (rank < (E_ / 2));
        bool m  = inactive ? fb : active;            // max(active, fb)

        float gated = fmaxf(logit, 0.0f);
        float me = m ? gated : -3.402823466e38f;     // -finfo(f32).max

        float mx = me;
        #pragma unroll
        for (int off = 1; off < 64; off <<= 1)
            mx = fmaxf(mx, __shfl_xor(mx, off, 64));
        float p = expf(me - mx);
        float sum = p;
        #pragma unroll
        for (int off = 1; off < 64; off <<= 1)
            sum += __shfl_xor(sum, off, 64);
        float prob = p / sum;

        out[OFF_LOGITS + b * E_ + e] = logit;
        ws_probs[b * E_ + e] = prob;
        ws_mask[b * E_ + e]  = m ? 1.0f : 0.0f;
        if (e == 0) ws_flags[b] = inactive ? 1.0f : 0.0f;
    }
}

// ---------------------------------------------------------------------------
// K3: broadcast probs/mask over T, float4 stores throughout.
// probs region is 16B-aligned at out[0]; mask region base OFF_MASK has
// OFF_MASK+3 16B-aligned -> shifted-float4 scheme, head(3)+tail(1) scalars.
// ---------------------------------------------------------------------------
__global__ __launch_bounds__(256) void k_bcast(const float* __restrict__ ws_probs,
                                               const float* __restrict__ ws_mask,
                                               const float* __restrict__ ws_flags,
                                               float* __restrict__ out) {
    int i = blockIdx.x * 256 + threadIdx.x;          // 0 .. NQ_-1
    // probs: float4 i covers flat 4i..4i+3 (same b,t; e-run inside row)
    int b = i >> 15;                                  // (4i) / (T_*E_)
    ((float4*)out)[i] = ((const float4*)ws_probs)[(b << 4) | (i & 15)];

    // mask: shifted float4 covers flat 3+4i .. 6+4i
    if (i < NQ_ - 1) {
        int f = 3 + 4 * i;
        float4 mv;
        mv.x = ws_mask[(((f + 0) >> 17) << 6) | ((f + 0) & 63)];
        mv.y = ws_mask[(((f + 1) >> 17) << 6) | ((f + 1) & 63)];
        mv.z = ws_mask[(((f + 2) >> 17) << 6) | ((f + 2) & 63)];
        mv.w = ws_mask[(((f + 3) >> 17) << 6) | ((f + 3) & 63)];
        ((float4*)(out + OFF_MASK + 3))[i] = mv;
    }
    if (i == 0) {
        out[OFF_MASK + 0] = ws_mask[0];
        out[OFF_MASK + 1] = ws_mask[1];
        out[OFF_MASK + 2] = ws_mask[2];
        out[OFF_MASK + NBT_ - 1] = ws_mask[B_ * E_ - 1];  // flat 4194303: b=31,e=63
        float fc = 0.f;
        #pragma unroll
        for (int k = 0; k < B_; ++k) fc += ws_flags[k];
        out[OFF_FB] = fc;                             // d_out is poisoned, must write
    }
}

extern "C" void kernel_launch(void* const* d_in, const int* in_sizes, int n_in,
                              void* d_out, int out_size, void* d_ws, size_t ws_size,
                              hipStream_t stream) {
    const float* hs    = (const float*)d_in[0];
    const float* sim   = (const float*)d_in[1];
    const float* gates = (const float*)d_in[2];
    float* out = (float*)d_out;
    float* ws  = (float*)d_ws;   // uses ~4.2 MB of scratch

    float* partial = ws + WS_PARTIAL;
    float* flags   = ws + WS_FLAGS;
    float* probs   = ws + WS_PROBS;
    float* maskv   = ws + WS_MASK;

    hipLaunchKernelGGL(k_partial, dim3(B_ * NT_ * C4_ / 256), dim3(256), 0, stream,
                       hs, partial);
    hipLaunchKernelGGL(k_gate, dim3(B_), dim3(256), 0, stream,
                       partial, sim, gates, out, probs, maskv, flags);
    hipLaunchKernelGGL(k_bcast, dim3(NQ_ / 256), dim3(256), 0, stream,
                       probs, maskv, flags, out);
}